// Round 9
// baseline (179.653 us; speedup 1.0000x reference)
//
#include <hip/hip_runtime.h>
#include <stdint.h>

// CriticNetwork (passing since R3):
//   value[b,i,m] = ve[i] + (sv[i] + w[i,m]*dv[m]) / 64
//   weights5[b,i,m,j] = w[b,i,j]                      (broadcast over m)
// w = sigmoid(K_b Q_b^T / sqrt(128)), K/Q = oa @ Wk^T / Wq^T
// u = Wv^T wf2, g = Wenc^T wf1, vas[j]=oa[j].u, dv[m]=(pol-act)[m].u[128:],
// ve[i]=obs[i].g, sv[i]=sum_j w[i,j] vas[j].
// R8 forensics: nt->regular stores changed nothing => nt theory dead. sw ~80us
// vs 21us write floor. The poison fill (shader kernel) hits 6.45 TB/s with a
// flat grid-stride store pattern; this round the 134 MB broadcast replicates
// that pattern exactly (critic_bc), with w as an L1/L2-resident 2 MB table.

#define BB 128
#define NN 64
#define OBSD 128
#define ACTD 16
#define DD 144
#define DKD 128
#define RS 168   // LDS row stride in bf16 for A/B tiles

typedef float f32x4 __attribute__((ext_vector_type(4)));
typedef short bf16x8 __attribute__((ext_vector_type(8)));

// ws layout (floats): K[b][i][c] at 0; QT[b][c][i] at WS_QT; vas/ve/dv;
// w[plane=b*64+i][j] at WS_W (2 MB).
#define WS_QT  1048576
#define WS_VAS 2097152
#define WS_VE  (WS_VAS + 8192)
#define WS_DV  (WS_VAS + 16384)
#define WS_W   (WS_VAS + 32768)

__device__ __forceinline__ unsigned int pack_bf2(float x, float y) {
  unsigned a = __float_as_uint(x), b = __float_as_uint(y);
  a = (a + 0x7fffu + ((a >> 16) & 1u)) >> 16;
  b = (b + 0x7fffu + ((b >> 16) & 1u)) >> 16;
  return a | (b << 16);
}
__device__ __forceinline__ float bf2f(unsigned short s) {
  return __uint_as_float(((unsigned)s) << 16);
}

// ---------------- kernel 1: K,Q via bf16 MFMA + per-row scalars ----------------
// grid 256: bid = b*2 + half. half0: K (+ u/g/vas/ve/dv). half1: Q -> QT.
__global__ __launch_bounds__(512, 2) void critic_kq(
    const float* __restrict__ obs, const float* __restrict__ pol, const float* __restrict__ act,
    const float* __restrict__ Wk, const float* __restrict__ Wq, const float* __restrict__ Wv,
    const float* __restrict__ Wenc, const float* __restrict__ Wfin,
    float* __restrict__ ws)
{
  __shared__ __align__(16) unsigned short s_A[NN * RS];    // oa bf16, 21.5 KB
  __shared__ __align__(16) unsigned short s_B[DKD * RS];   // W  bf16, 43 KB
  __shared__ float s_dpa[NN][ACTD];
  __shared__ float s_u[DD];
  __shared__ float s_g[OBSD];

  const int tid = threadIdx.x;
  const int b = blockIdx.x >> 1;
  const int half = blockIdx.x & 1;

  // ---- stage A = oa[b] (64 x 144 f32 -> bf16), pad cols 144..159 = 0
  {
    const float4* obs4 = (const float4*)(obs + (size_t)b * NN * OBSD);
    for (int idx = tid; idx < 2048; idx += 512) {
      float4 v = obs4[idx];
      int row = idx >> 5, c4 = (idx & 31) * 4;
      *(uint2*)&s_A[row * RS + c4] = make_uint2(pack_bf2(v.x, v.y), pack_bf2(v.z, v.w));
    }
    const float4* act4 = (const float4*)(act + (size_t)b * NN * ACTD);
    const float4* pol4 = (const float4*)(pol + (size_t)b * NN * ACTD);
    for (int idx = tid; idx < 256; idx += 512) {
      float4 a = act4[idx];
      int row = idx >> 2, c4 = OBSD + (idx & 3) * 4;
      *(uint2*)&s_A[row * RS + c4] = make_uint2(pack_bf2(a.x, a.y), pack_bf2(a.z, a.w));
      if (half == 0) {
        float4 p = pol4[idx];
        int t0 = (idx & 3) * 4;
        s_dpa[row][t0 + 0] = p.x - a.x; s_dpa[row][t0 + 1] = p.y - a.y;
        s_dpa[row][t0 + 2] = p.z - a.z; s_dpa[row][t0 + 3] = p.w - a.w;
      }
    }
    for (int idx = tid; idx < 256; idx += 512) {
      int row = idx >> 2, c4 = DD + (idx & 3) * 4;
      *(uint2*)&s_A[row * RS + c4] = make_uint2(0u, 0u);
    }
  }
  // ---- stage B = W(half) (128 x 144 -> bf16) + zero pad
  {
    const float4* W4 = (const float4*)(half ? Wq : Wk);
    for (int idx = tid; idx < 4096; idx += 512) {
      int row = idx >> 5, g = idx & 31;
      float4 v = W4[row * 36 + g];
      *(uint2*)&s_B[row * RS + g * 4] = make_uint2(pack_bf2(v.x, v.y), pack_bf2(v.z, v.w));
    }
    for (int idx = tid; idx < 512; idx += 512) {
      int row = idx >> 2, g = idx & 3;
      float4 v = W4[row * 36 + 32 + g];
      *(uint2*)&s_B[row * RS + OBSD + g * 4] = make_uint2(pack_bf2(v.x, v.y), pack_bf2(v.z, v.w));
    }
    for (int idx = tid; idx < 512; idx += 512) {
      int row = idx >> 2, c4 = DD + (idx & 3) * 4;
      *(uint2*)&s_B[row * RS + c4] = make_uint2(0u, 0u);
    }
  }
  // ---- u, g (half0): coalesced L2 loads, 8-way ILP
  if (half == 0) {
    if (tid < DD) {
      float a0=0.f,a1=0.f,a2=0.f,a3=0.f,a4=0.f,a5=0.f,a6=0.f,a7=0.f;
      for (int c = 0; c < DKD; c += 8) {
        a0 += Wv[(size_t)(c+0)*DD + tid] * Wfin[OBSD + c + 0];
        a1 += Wv[(size_t)(c+1)*DD + tid] * Wfin[OBSD + c + 1];
        a2 += Wv[(size_t)(c+2)*DD + tid] * Wfin[OBSD + c + 2];
        a3 += Wv[(size_t)(c+3)*DD + tid] * Wfin[OBSD + c + 3];
        a4 += Wv[(size_t)(c+4)*DD + tid] * Wfin[OBSD + c + 4];
        a5 += Wv[(size_t)(c+5)*DD + tid] * Wfin[OBSD + c + 5];
        a6 += Wv[(size_t)(c+6)*DD + tid] * Wfin[OBSD + c + 6];
        a7 += Wv[(size_t)(c+7)*DD + tid] * Wfin[OBSD + c + 7];
      }
      s_u[tid] = ((a0+a1)+(a2+a3)) + ((a4+a5)+(a6+a7));
    } else if (tid < DD + OBSD) {
      const int d = tid - DD;
      float a0=0.f,a1=0.f,a2=0.f,a3=0.f,a4=0.f,a5=0.f,a6=0.f,a7=0.f;
      for (int c = 0; c < 128; c += 8) {
        a0 += Wenc[(size_t)(c+0)*OBSD + d] * Wfin[c + 0];
        a1 += Wenc[(size_t)(c+1)*OBSD + d] * Wfin[c + 1];
        a2 += Wenc[(size_t)(c+2)*OBSD + d] * Wfin[c + 2];
        a3 += Wenc[(size_t)(c+3)*OBSD + d] * Wfin[c + 3];
        a4 += Wenc[(size_t)(c+4)*OBSD + d] * Wfin[c + 4];
        a5 += Wenc[(size_t)(c+5)*OBSD + d] * Wfin[c + 5];
        a6 += Wenc[(size_t)(c+6)*OBSD + d] * Wfin[c + 6];
        a7 += Wenc[(size_t)(c+7)*OBSD + d] * Wfin[c + 7];
      }
      s_g[d] = ((a0+a1)+(a2+a3)) + ((a4+a5)+(a6+a7));
    }
  }
  __syncthreads();

  // ---- MFMA: wave w -> i-tile (w&3)*16, N-tiles (w>>2)*4 .. +3
  {
    const int wv = tid >> 6, lane = tid & 63;
    const int i0 = (wv & 3) * 16;
    const int n0 = (wv >> 2) * 4;
    const int m = lane & 15, q = lane >> 4;
    f32x4 acc[4];
    #pragma unroll
    for (int t = 0; t < 4; ++t) acc[t] = (f32x4){0.f, 0.f, 0.f, 0.f};
    #pragma unroll
    for (int ks = 0; ks < 5; ++ks) {
      const int koff = ks * 32 + q * 8;
      bf16x8 a = *(const bf16x8*)&s_A[(i0 + m) * RS + koff];
      #pragma unroll
      for (int t = 0; t < 4; ++t) {
        bf16x8 bb = *(const bf16x8*)&s_B[((n0 + t) * 16 + m) * RS + koff];
        acc[t] = __builtin_amdgcn_mfma_f32_16x16x32_bf16(a, bb, acc[t], 0, 0, 0);
      }
    }
    if (half == 0) {
      float* kb = ws + (size_t)b * 8192;
      #pragma unroll
      for (int t = 0; t < 4; ++t)
        #pragma unroll
        for (int r = 0; r < 4; ++r)
          kb[(i0 + q * 4 + r) * 128 + (n0 + t) * 16 + m] = acc[t][r];
    } else {
      float* qb = ws + WS_QT + (size_t)b * 8192;   // QT[c][i]
      #pragma unroll
      for (int t = 0; t < 4; ++t)
        *(f32x4*)&qb[((n0 + t) * 16 + m) * 64 + i0 + q * 4] = acc[t];
    }
  }

  // ---- per-row scalars (half0)
  if (half == 0) {
    if (tid < 64) {
      float a = 0.f;
      for (int d = 0; d < DD; ++d) a += bf2f(s_A[tid * RS + d]) * s_u[d];
      ws[WS_VAS + b * 64 + tid] = a;
    } else if (tid < 128) {
      const int i = tid - 64;
      float a = 0.f;
      for (int d = 0; d < OBSD; ++d) a += bf2f(s_A[i * RS + d]) * s_g[d];
      ws[WS_VE + b * 64 + i] = a;
    } else if (tid < 192) {
      const int i = tid - 128;
      float a = 0.f;
      #pragma unroll
      for (int t = 0; t < ACTD; ++t) a += s_dpa[i][t] * s_u[OBSD + t];
      ws[WS_DV + b * 64 + i] = a;
    }
  }
}

// -------- kernel 2: scores + sigmoid + sv + value; w -> ws (no broadcast) --------
// grid 512: bid = b*4 + ig; 16 i-rows per block.
__global__ __launch_bounds__(256, 3) void critic_w(
    const float* __restrict__ ws_in, float* __restrict__ ws_w, float* __restrict__ out)
{
  __shared__ __align__(16) float s_qT[DKD][64];
  __shared__ __align__(16) float s_k[16][132];
  __shared__ __align__(16) float s_w[16][68];
  __shared__ float s_vas[64], s_dv[64], s_ve[16], s_sv[16];

  const int t = threadIdx.x;
  const int b = blockIdx.x >> 2;
  const int i0 = (blockIdx.x & 3) * 16;

  {
    const float4* qt4 = (const float4*)(ws_in + WS_QT + (size_t)b * 8192);
    for (int idx = t; idx < 2048; idx += 256) {
      int c = idx >> 4, i4 = (idx & 15) * 4;
      *(float4*)&s_qT[c][i4] = qt4[idx];
    }
    const float4* k4 = (const float4*)(ws_in + (size_t)b * 8192 + (size_t)i0 * 128);
    for (int idx = t; idx < 512; idx += 256) {
      int r = idx >> 5, c4 = (idx & 31) * 4;
      *(float4*)&s_k[r][c4] = k4[idx];
    }
    if (t < 64)            s_vas[t] = ws_in[WS_VAS + b * 64 + t];
    else if (t < 128)      s_dv[t - 64] = ws_in[WS_DV + b * 64 + (t - 64)];
    else if (t < 144)      s_ve[t - 128] = ws_in[WS_VE + b * 64 + i0 + (t - 128)];
  }
  __syncthreads();

  {
    const int wv = t >> 6, j = t & 63;
    float sc0 = 0.f, sc1 = 0.f, sc2 = 0.f, sc3 = 0.f;
    #pragma unroll 4
    for (int d0 = 0; d0 < DKD; d0 += 4) {
      float q0 = s_qT[d0 + 0][j], q1 = s_qT[d0 + 1][j];
      float q2 = s_qT[d0 + 2][j], q3 = s_qT[d0 + 3][j];
      float4 k0 = *(const float4*)&s_k[wv * 4 + 0][d0];
      float4 k1 = *(const float4*)&s_k[wv * 4 + 1][d0];
      float4 k2 = *(const float4*)&s_k[wv * 4 + 2][d0];
      float4 k3 = *(const float4*)&s_k[wv * 4 + 3][d0];
      sc0 += k0.x * q0 + k0.y * q1 + k0.z * q2 + k0.w * q3;
      sc1 += k1.x * q0 + k1.y * q1 + k1.z * q2 + k1.w * q3;
      sc2 += k2.x * q0 + k2.y * q1 + k2.z * q2 + k2.w * q3;
      sc3 += k3.x * q0 + k3.y * q1 + k3.z * q2 + k3.w * q3;
    }
    const float kk = 0.08838834764831845f;  // 1/sqrt(128)
    s_w[wv * 4 + 0][j] = 1.0f / (1.0f + __expf(-sc0 * kk));
    s_w[wv * 4 + 1][j] = 1.0f / (1.0f + __expf(-sc1 * kk));
    s_w[wv * 4 + 2][j] = 1.0f / (1.0f + __expf(-sc2 * kk));
    s_w[wv * 4 + 3][j] = 1.0f / (1.0f + __expf(-sc3 * kk));
  }
  __syncthreads();

  if (t < 16) {
    float a = 0.f;
    for (int j = 0; j < 64; ++j) a += s_w[t][j] * s_vas[j];
    s_sv[t] = a;
  }
  __syncthreads();

  // value rows [b, i0+r, m]
  {
    const int r = t >> 4, m4 = (t & 15) * 4;
    float4 v;
    v.x = s_ve[r] + (s_sv[r] + s_w[r][m4 + 0] * s_dv[m4 + 0]) * (1.0f / 64.0f);
    v.y = s_ve[r] + (s_sv[r] + s_w[r][m4 + 1] * s_dv[m4 + 1]) * (1.0f / 64.0f);
    v.z = s_ve[r] + (s_sv[r] + s_w[r][m4 + 2] * s_dv[m4 + 2]) * (1.0f / 64.0f);
    v.w = s_ve[r] + (s_sv[r] + s_w[r][m4 + 3] * s_dv[m4 + 3]) * (1.0f / 64.0f);
    *(float4*)(out + ((size_t)(b * 64 + i0 + r) * 64 + m4)) = v;
  }

  // w rows -> ws (2 MB table for the broadcast kernel), coalesced
  for (int idx = t; idx < 1024; idx += 256) {
    int r = idx >> 6, j = idx & 63;
    ws_w[(size_t)(b * 64 + i0 + r) * 64 + j] = s_w[r][j];
  }
}

// -------- kernel 3: flat grid-stride broadcast (replicates the fill's pattern) --
// out5 flat float4 f: plane = f>>10, j4 = f&15; value = w[plane][j4*4..+3].
// 4096 blocks x 256 threads, 8 float4 per thread, pure linear streaming stores.
__global__ __launch_bounds__(256, 4) void critic_bc(
    const float* __restrict__ ws_w, float* __restrict__ out)
{
  const float4* w4 = (const float4*)ws_w;
  float4* o4 = (float4*)(out + (size_t)BB * NN * NN);
  const unsigned total = 8388608u;                    // 128*64*64*64/4
  const unsigned stride = gridDim.x * blockDim.x;
  for (unsigned f = blockIdx.x * blockDim.x + threadIdx.x; f < total; f += stride) {
    o4[f] = w4[((f >> 10) << 4) + (f & 15)];          // plane*16 + j4 (L1/L2 hit)
  }
}

extern "C" void kernel_launch(void* const* d_in, const int* in_sizes, int n_in,
                              void* d_out, int out_size, void* d_ws, size_t ws_size,
                              hipStream_t stream) {
  (void)in_sizes; (void)n_in; (void)out_size; (void)ws_size;
  const float* obs  = (const float*)d_in[0];
  const float* pol  = (const float*)d_in[1];
  const float* act  = (const float*)d_in[2];
  const float* Wk   = (const float*)d_in[3];
  const float* Wq   = (const float*)d_in[4];
  const float* Wv   = (const float*)d_in[5];
  const float* Wenc = (const float*)d_in[6];
  const float* Wfin = (const float*)d_in[7];
  float* out = (float*)d_out;
  float* ws  = (float*)d_ws;
  hipLaunchKernelGGL(critic_kq, dim3(BB * 2), dim3(512), 0, stream,
                     obs, pol, act, Wk, Wq, Wv, Wenc, Wfin, ws);
  hipLaunchKernelGGL(critic_w, dim3(BB * 4), dim3(256), 0, stream,
                     ws, ws + WS_W, out);
  hipLaunchKernelGGL(critic_bc, dim3(4096), dim3(256), 0, stream,
                     ws + WS_W, out);
}

// Round 10
// 165.482 us; speedup vs baseline: 1.0856x; 1.0856x over previous
//
#include <hip/hip_runtime.h>
#include <stdint.h>

// CriticNetwork: value[b,i,m] = ve[i] + (sv[i] + w[i,m]*dv[m])/64;
// weights5[b,i,m,j] = w[b,i,j]. w = sigmoid(scores/sqrt(128)),
// scores[i,j] = K[i].Q[j] = oa_i (Wk^T Wq) oa_j^T  -> MT trick: no K/Q GEMMs.
// setup: MT[e][d] = sum_c Wk[c,d]Wq[c,e] (bf16), u = Wv^T wf2, g = Wenc^T wf1.
// fused (512 blk x 512 thr, 72KB LDS): T = oa16 x MT^T (MFMA), scores = T x oa^T
// (MFMA), sigmoid, vas/ve/dv/sv, value rows, plane broadcast. 2 dispatches.
// R9 ledger: every broadcast variant ~80us (1.7 TB/s) vs fill 6.4 TB/s; R3
// WRITE_SIZE showed poison-drain bleed => testing global-HBM-bound theory with
// one big visible kernel.

#define BB 128
#define NN 64
#define OBSD 128
#define ACTD 16
#define DD 144
#define DKD 128
#define RS 168   // LDS bf16 row stride: 84 dwords = 20 mod 32 -> conflict-free frags

typedef float f32x4 __attribute__((ext_vector_type(4)));
typedef short bf16x8 __attribute__((ext_vector_type(8)));

// ws: ushort MT[144*160] at 0; float u[144] at F_U; float g[128] at F_G
#define F_U 16384
#define F_G (F_U + 256)

__device__ __forceinline__ unsigned short bf1(float x) {
  unsigned u = __float_as_uint(x);
  return (unsigned short)((u + 0x7fffu + ((u >> 16) & 1u)) >> 16);
}
__device__ __forceinline__ unsigned int pack_bf2(float x, float y) {
  return (unsigned)bf1(x) | ((unsigned)bf1(y) << 16);
}
__device__ __forceinline__ float bf2f(unsigned short s) {
  return __uint_as_float(((unsigned)s) << 16);
}

// ---------------- setup: MT (144 rows) + u + g ----------------
__global__ __launch_bounds__(256) void critic_setup(
    const float* __restrict__ Wk, const float* __restrict__ Wq,
    const float* __restrict__ Wv, const float* __restrict__ Wenc,
    const float* __restrict__ Wfin, float* __restrict__ ws)
{
  const int bid = blockIdx.x, t = threadIdx.x;
  if (bid < DD) {                       // MT row e: MT[e][d] = sum_c Wk[c,d]Wq[c,e]
    const int e = bid;
    if (t < 160) {
      float acc = 0.f;
      if (t < DD) {
        float a0=0.f,a1=0.f,a2=0.f,a3=0.f;
        for (int c = 0; c < DKD; c += 4) {
          a0 += Wk[(c+0)*DD + t] * Wq[(c+0)*DD + e];
          a1 += Wk[(c+1)*DD + t] * Wq[(c+1)*DD + e];
          a2 += Wk[(c+2)*DD + t] * Wq[(c+2)*DD + e];
          a3 += Wk[(c+3)*DD + t] * Wq[(c+3)*DD + e];
        }
        acc = (a0+a1)+(a2+a3);
      }
      ((unsigned short*)ws)[e * 160 + t] = bf1(acc);
    }
  } else if (bid == DD) {               // u[t] = sum_c Wv[c,t] * Wfin[128+c]
    if (t < DD) {
      float a0=0.f,a1=0.f,a2=0.f,a3=0.f;
      for (int c = 0; c < DKD; c += 4) {
        a0 += Wv[(c+0)*DD + t] * Wfin[OBSD + c + 0];
        a1 += Wv[(c+1)*DD + t] * Wfin[OBSD + c + 1];
        a2 += Wv[(c+2)*DD + t] * Wfin[OBSD + c + 2];
        a3 += Wv[(c+3)*DD + t] * Wfin[OBSD + c + 3];
      }
      ws[F_U + t] = (a0+a1)+(a2+a3);
    }
  } else {                              // g[d] = sum_c Wenc[c,d] * Wfin[c]
    if (t < OBSD) {
      float a0=0.f,a1=0.f,a2=0.f,a3=0.f;
      for (int c = 0; c < 128; c += 4) {
        a0 += Wenc[(c+0)*OBSD + t] * Wfin[c + 0];
        a1 += Wenc[(c+1)*OBSD + t] * Wfin[c + 1];
        a2 += Wenc[(c+2)*OBSD + t] * Wfin[c + 2];
        a3 += Wenc[(c+3)*OBSD + t] * Wfin[c + 3];
      }
      ws[F_G + t] = (a0+a1)+(a2+a3);
    }
  }
}

// ---------------- fused: everything else, one dispatch ----------------
// grid 512: bid = b*4 + p; i0 = p*16. 512 threads (8 waves). 72 KB LDS, 2 blk/CU.
__global__ __launch_bounds__(512, 2) void critic_fused(
    const float* __restrict__ obs, const float* __restrict__ pol,
    const float* __restrict__ act, const float* __restrict__ ws,
    float* __restrict__ out)
{
  __shared__ __align__(16) unsigned short s_oa[NN * RS];      // 21504 B
  __shared__ __align__(16) unsigned short s_MT[DD * RS];      // 48384 B; later: s_T + s_w
  __shared__ __align__(16) unsigned short s_dpa[NN * ACTD];   // 2048 B (bf16)
  __shared__ float s_u[DD];
  __shared__ float s_g[OBSD];
  __shared__ float s_vas[NN], s_dv[NN], s_ve[16], s_sv[16];

  unsigned short* s_T = s_MT;                       // 16 rows x RS (alias, after MT dead)
  float* s_w = (float*)(s_MT + 16 * RS);            // [16][68] f32 (alias)

  const int tid = threadIdx.x;
  const int b = blockIdx.x >> 2;
  const int i0 = (blockIdx.x & 3) * 16;

  // ---- stage oa (bf16), dpa (bf16), MT (from ws), u, g
  {
    const float4* obs4 = (const float4*)(obs + (size_t)b * NN * OBSD);
    for (int idx = tid; idx < 2048; idx += 512) {   // 64 rows x 32 f4
      float4 v = obs4[idx];
      int row = idx >> 5, c4 = (idx & 31) * 4;
      *(uint2*)&s_oa[row * RS + c4] = make_uint2(pack_bf2(v.x, v.y), pack_bf2(v.z, v.w));
    }
    if (tid < 256) {                                // act/pol: 64 rows x 4 f4
      const float4* act4 = (const float4*)(act + (size_t)b * NN * ACTD);
      const float4* pol4 = (const float4*)(pol + (size_t)b * NN * ACTD);
      float4 a = act4[tid], pp = pol4[tid];
      int row = tid >> 2, t0 = (tid & 3) * 4;
      *(uint2*)&s_oa[row * RS + OBSD + t0] = make_uint2(pack_bf2(a.x, a.y), pack_bf2(a.z, a.w));
      *(uint2*)&s_dpa[row * ACTD + t0] =
          make_uint2(pack_bf2(pp.x - a.x, pp.y - a.y), pack_bf2(pp.z - a.z, pp.w - a.w));
    } else if (tid < 512) {                         // zero-pad oa cols 144..159
      int idx = tid - 256;                          // 256 = 64 rows x 4 uint2
      int row = idx >> 2, c4 = DD + (idx & 3) * 4;
      *(uint2*)&s_oa[row * RS + c4] = make_uint2(0u, 0u);
    }
    const uint4* mt4 = (const uint4*)ws;            // 144 rows x 20 uint4 (8 bf16)
    for (int idx = tid; idx < 2880; idx += 512) {
      int row = idx / 20, g4 = idx - row * 20;
      *(uint4*)&s_MT[row * RS + g4 * 8] = mt4[idx];
    }
    for (int idx = tid; idx < 288; idx += 512) {    // zero-pad MT cols 144..159
      int row = idx >> 1, h = idx & 1;
      *(uint4*)&s_MT[row * RS + DD + h * 8] = make_uint4(0u, 0u, 0u, 0u);
    }
    if (tid < DD)            s_u[tid] = ws[F_U + tid];
    else if (tid < DD + OBSD) s_g[tid - DD] = ws[F_G + (tid - DD)];
  }
  __syncthreads();

  const int wv = tid >> 6, lane = tid & 63;
  const int m = lane & 15, q = lane >> 4;

  // ---- T = oa[i0..i0+15] x MT^T : 9 e-tiles; wave wv -> tile wv (+ wave0 -> tile 8)
  f32x4 accT = (f32x4){0.f, 0.f, 0.f, 0.f};
  f32x4 accT8 = (f32x4){0.f, 0.f, 0.f, 0.f};
  #pragma unroll
  for (int ks = 0; ks < 5; ++ks) {
    const int koff = ks * 32 + q * 8;
    bf16x8 a = *(const bf16x8*)&s_oa[(i0 + m) * RS + koff];
    bf16x8 bb = *(const bf16x8*)&s_MT[(wv * 16 + m) * RS + koff];
    accT = __builtin_amdgcn_mfma_f32_16x16x32_bf16(a, bb, accT, 0, 0, 0);
    if (wv == 0) {
      bf16x8 b8 = *(const bf16x8*)&s_MT[(128 + m) * RS + koff];
      accT8 = __builtin_amdgcn_mfma_f32_16x16x32_bf16(a, b8, accT8, 0, 0, 0);
    }
  }
  __syncthreads();                                  // all MT reads done -> alias ok

  // ---- write T (bf16) into aliased region; zero-pad T cols 144..159
  #pragma unroll
  for (int r = 0; r < 4; ++r)
    s_T[(q * 4 + r) * RS + wv * 16 + m] = bf1(accT[r]);
  if (wv == 0)
    #pragma unroll
    for (int r = 0; r < 4; ++r)
      s_T[(q * 4 + r) * RS + 128 + m] = bf1(accT8[r]);
  if (tid < 32) {
    int row = tid >> 1, h = tid & 1;
    *(uint4*)&s_T[row * RS + DD + h * 8] = make_uint4(0u, 0u, 0u, 0u);
  }
  __syncthreads();

  // ---- scores (waves 0-3, j-tile = wv) || vas/dv/ve (waves 4-6)
  if (wv < 4) {
    f32x4 sc = (f32x4){0.f, 0.f, 0.f, 0.f};
    #pragma unroll
    for (int ks = 0; ks < 5; ++ks) {
      const int koff = ks * 32 + q * 8;
      bf16x8 a = *(const bf16x8*)&s_T[m * RS + koff];
      bf16x8 bb = *(const bf16x8*)&s_oa[(wv * 16 + m) * RS + koff];
      sc = __builtin_amdgcn_mfma_f32_16x16x32_bf16(a, bb, sc, 0, 0, 0);
    }
    const float kk = 0.08838834764831845f;          // 1/sqrt(128)
    #pragma unroll
    for (int r = 0; r < 4; ++r)
      s_w[(q * 4 + r) * 68 + wv * 16 + m] = 1.0f / (1.0f + __expf(-sc[r] * kk));
  } else if (wv == 4) {                             // dv[m] = dpa[m].u[128:144]
    float a = 0.f;
    #pragma unroll
    for (int t = 0; t < ACTD; ++t) a += bf2f(s_dpa[lane * ACTD + t]) * s_u[OBSD + t];
    s_dv[lane] = a;
  } else if (wv == 5) {                             // vas[j] = oa[j].u
    float a = 0.f;
    for (int d = 0; d < DD; ++d) a += bf2f(s_oa[lane * RS + d]) * s_u[d];
    s_vas[lane] = a;
  } else if (wv == 6 && lane < 16) {                // ve for this block's rows
    float a = 0.f;
    for (int d = 0; d < OBSD; ++d) a += bf2f(s_oa[(i0 + lane) * RS + d]) * s_g[d];
    s_ve[lane] = a;
  }
  __syncthreads();

  if (tid < 16) {                                   // sv[i] = sum_j w[i,j] vas[j]
    float a = 0.f;
    for (int j = 0; j < NN; ++j) a += s_w[tid * 68 + j] * s_vas[j];
    s_sv[tid] = a;
  }
  __syncthreads();

  // ---- value rows [b, i0+r, :]
  if (tid < 256) {
    const int r = tid >> 4, m4 = (tid & 15) * 4;
    float4 v;
    v.x = s_ve[r] + (s_sv[r] + s_w[r * 68 + m4 + 0] * s_dv[m4 + 0]) * (1.0f / 64.0f);
    v.y = s_ve[r] + (s_sv[r] + s_w[r * 68 + m4 + 1] * s_dv[m4 + 1]) * (1.0f / 64.0f);
    v.z = s_ve[r] + (s_sv[r] + s_w[r * 68 + m4 + 2] * s_dv[m4 + 2]) * (1.0f / 64.0f);
    v.w = s_ve[r] + (s_sv[r] + s_w[r * 68 + m4 + 3] * s_dv[m4 + 3]) * (1.0f / 64.0f);
    *(float4*)(out + ((size_t)(b * 64 + i0 + r) * 64 + m4)) = v;
  }

  // ---- broadcast: 16 planes x 16 KB, coalesced float4 (2 per thread per plane)
  float* w5 = out + (size_t)BB * NN * NN;
  #pragma unroll 4
  for (int r = 0; r < 16; ++r) {
    const float4 wv4 = *(const float4*)&s_w[r * 68 + (tid & 15) * 4];
    float4* p4 = (float4*)(w5 + ((size_t)(b * 64 + i0 + r) << 12));
    p4[tid]       = wv4;
    p4[tid + 512] = wv4;
  }
}

extern "C" void kernel_launch(void* const* d_in, const int* in_sizes, int n_in,
                              void* d_out, int out_size, void* d_ws, size_t ws_size,
                              hipStream_t stream) {
  (void)in_sizes; (void)n_in; (void)out_size; (void)ws_size;
  const float* obs  = (const float*)d_in[0];
  const float* pol  = (const float*)d_in[1];
  const float* act  = (const float*)d_in[2];
  const float* Wk   = (const float*)d_in[3];
  const float* Wq   = (const float*)d_in[4];
  const float* Wv   = (const float*)d_in[5];
  const float* Wenc = (const float*)d_in[6];
  const float* Wfin = (const float*)d_in[7];
  float* out = (float*)d_out;
  float* ws  = (float*)d_ws;
  hipLaunchKernelGGL(critic_setup, dim3(DD + 2), dim3(256), 0, stream,
                     Wk, Wq, Wv, Wenc, Wfin, ws);
  hipLaunchKernelGGL(critic_fused, dim3(BB * 4), dim3(512), 0, stream,
                     obs, pol, act, ws, out);
}